// Round 3
// baseline (233.768 us; speedup 1.0000x reference)
//
#include <hip/hip_runtime.h>
#include <hip/hip_bf16.h>

// SurfaceLoss: 16x256x256 grid through 3->128->128->128->1 tanh MLP, MSE vs images.
// R13: R11's channel-paired waves DONE RIGHT. Wave = (32 channels) x (64 points);
//      each LDS H-fragment read feeds TWO MFMAs -> ds_read_b128 per wave halves
//      (64 -> 32 total). Unlike R11 (which refetched W per-ks from L2 INSIDE the
//      MFMA loop and stalled every barrier-synced wave: 184us), BOTH W half-tile
//      fragment sets are preloaded into registers outside the loops (R12's proven
//      prefetch placement). Costs +16 VGPRs -> __launch_bounds__(512,6), 6 waves/
//      SIMD. LDS pipe audit: reads+conflicts+writes ~72% of CU cycles, conflicts
//      alone 22% (1.89e7/dispatch, proven read-proportional by R11) — this halves
//      both. Frozen: R11/R12 layer-1 exp2 recurrence, R9 dual operand-swapped MFMA
//      (D[ch][point]), fused epi3+layer4, exp2+rcp tanh, fence-free last-block
//      reduction, (512 thr), LDA 136, KS folding, R10 v_perm pack2bf.

#define BATCH 16
#define LDA 136                 // padded LDS row stride (bf16 elems)
#define STEP (256.0f / 255.0f)  // linspace(-128,128,256) step
#define KS 2.8853900817779268f  // 2*log2(e): tanh(z) = 1 - 2/(exp2(KS*z)+1)

typedef __bf16 v8bf __attribute__((ext_vector_type(8)));
typedef float  v4f  __attribute__((ext_vector_type(4)));

__device__ __forceinline__ unsigned short f2bf(float f) {   // round-nearest (prep only)
    unsigned int u = __float_as_uint(f);
    unsigned int r = (u + 0x7fffu + ((u >> 16) & 1u)) >> 16;
    return (unsigned short)r;
}

// hot-path pack: {hi16(b), hi16(a)} in ONE v_perm_b32 (bf16 truncation).
#if __has_builtin(__builtin_amdgcn_perm)
__device__ __forceinline__ unsigned int pack2bf(float a, float b) {
    return __builtin_amdgcn_perm(__float_as_uint(b), __float_as_uint(a), 0x07060302u);
}
#else
__device__ __forceinline__ unsigned int pack2bf(float a, float b) {
    return (__float_as_uint(a) >> 16) | (__float_as_uint(b) & 0xffff0000u);
}
#endif

// input pre-scaled by KS; R6 measured-best form. exp2(+big)->inf->rcp->0 exact.
__device__ __forceinline__ float tanh_pre(float zk) {
    float e = __builtin_amdgcn_exp2f(zk);
    float r = __builtin_amdgcn_rcpf(e + 1.f);
    return fmaf(-2.f, r, 1.f);
}

// ---- prep: W2,W3 (128x128 fp32 [k][n]) -> bf16 [n][k] pre-scaled by KS;
//      zero partials + counter ----
__global__ __launch_bounds__(256) void prep_kernel(
    const float* __restrict__ W2, const float* __restrict__ W3,
    unsigned short* __restrict__ w2t, unsigned short* __restrict__ w3t,
    float* __restrict__ partials, unsigned int* __restrict__ counter)
{
    int o = blockIdx.x * 256 + threadIdx.x;
    if (o < 1024) partials[o] = 0.f;
    if (o == 0) *counter = 0u;
    const float* src = (o < 16384) ? W2 : W3;
    unsigned short* dst = (o < 16384) ? w2t : w3t;
    int e = o & 16383;
    int k = e >> 7, n = e & 127;
    dst[n * 128 + k] = f2bf(src[e] * KS);
}

// ---- main: one block (512 thr, 8 waves) = 128 consecutive pixels of one image row ----
__global__ __launch_bounds__(512, 6) void main_kernel(
    const float* __restrict__ images,
    const float* __restrict__ W1, const float* __restrict__ b1,
    const float* __restrict__ b2, const float* __restrict__ b3,
    const float* __restrict__ W4, const float* __restrict__ b4,
    const int*   __restrict__ np,
    const unsigned short* __restrict__ w2t,
    const unsigned short* __restrict__ w3t,
    float* __restrict__ partials, unsigned int* __restrict__ counter,
    float* __restrict__ out)
{
    __shared__ unsigned short A[128 * LDA];
    __shared__ float P[4][128];       // per-cg partial dots (32 chs each) per point
    __shared__ float red[8];
    __shared__ unsigned int isLastS;

    const int tid  = threadIdx.x;
    const int lane = tid & 63;
    const int w    = tid >> 6;        // wave 0..7
    const int l15  = lane & 15;
    const int quad = lane >> 4;

    const int bid = blockIdx.x;
    const int b   = bid >> 9;          // 512 blocks per image
    const int rem = bid & 511;
    const int r   = rem >> 1;          // image row (x index)
    const int c0  = (rem & 1) << 7;    // y base

    const float tv = (float)(b + np[0] * BATCH);
    const float xv = -128.f + (float)r * STEP;

    // ---- layer 1 (fp32, pre-scaled by KS): 4 cols x 8 points, e-RECURRENCE ----
    {
        const int lo = tid & 31, hi = tid >> 5;
        const int j0 = lo * 4, p0 = hi * 8;
        float4 wx = *(const float4*)(W1 + j0);
        float4 wy = *(const float4*)(W1 + 128 + j0);
        float4 wt = *(const float4*)(W1 + 256 + j0);
        float4 bb = *(const float4*)(b1 + j0);
        const float yv0 = fmaf((float)(c0 + p0), STEP, -128.f);
        float z0 = fmaf(yv0, KS * wy.x, KS * fmaf(xv, wx.x, fmaf(tv, wt.x, bb.x)));
        float z1 = fmaf(yv0, KS * wy.y, KS * fmaf(xv, wx.y, fmaf(tv, wt.y, bb.y)));
        float z2 = fmaf(yv0, KS * wy.z, KS * fmaf(xv, wx.z, fmaf(tv, wt.z, bb.z)));
        float z3 = fmaf(yv0, KS * wy.w, KS * fmaf(xv, wx.w, fmaf(tv, wt.w, bb.w)));
        float e0 = __builtin_amdgcn_exp2f(z0);
        float e1 = __builtin_amdgcn_exp2f(z1);
        float e2 = __builtin_amdgcn_exp2f(z2);
        float e3 = __builtin_amdgcn_exp2f(z3);
        const float E0 = __builtin_amdgcn_exp2f(KS * STEP * wy.x);
        const float E1 = __builtin_amdgcn_exp2f(KS * STEP * wy.y);
        const float E2 = __builtin_amdgcn_exp2f(KS * STEP * wy.z);
        const float E3 = __builtin_amdgcn_exp2f(KS * STEP * wy.w);
        #pragma unroll
        for (int pi = 0; pi < 8; ++pi) {
            float h0 = fmaf(-2.f, __builtin_amdgcn_rcpf(e0 + 1.f), 1.f);
            float h1 = fmaf(-2.f, __builtin_amdgcn_rcpf(e1 + 1.f), 1.f);
            float h2 = fmaf(-2.f, __builtin_amdgcn_rcpf(e2 + 1.f), 1.f);
            float h3 = fmaf(-2.f, __builtin_amdgcn_rcpf(e3 + 1.f), 1.f);
            uint2 u = make_uint2(pack2bf(h0, h1), pack2bf(h2, h3));
            *(uint2*)&A[(p0 + pi) * LDA + j0] = u;   // 8B store, conflict-free
            e0 *= E0; e1 *= E1; e2 *= E2; e3 *= E3;
        }
    }
    __syncthreads();

    // wave decomposition: cg = 32-channel group, ph = 64-point half.
    const int cg   = w & 3;
    const int ph   = w >> 2;
    const int colw = cg * 32 + l15;        // A-operand m-row for half a (half b: +16)
    const int ch4  = cg * 32 + quad * 4;   // C/D 4-channel base (half b: +16)

    // ---- W2 A-fragments, BOTH 16-ch halves, preloaded to registers (L2-hot) ----
    v8bf wfa[4], wfb[4];
    #pragma unroll
    for (int ks = 0; ks < 4; ++ks) {
        wfa[ks] = *(const v8bf*)(w2t + colw * 128 + ks * 32 + quad * 8);
        wfb[ks] = *(const v8bf*)(w2t + (colw + 16) * 128 + ks * 32 + quad * 8);
    }

    // ---- layer 2 MFMA, swapped: D[ch][point]; each af read feeds 2 MFMAs ----
    v4f acc[2][4];
    {
        float4 ba = *(const float4*)(b2 + ch4);
        float4 bc = *(const float4*)(b2 + ch4 + 16);
        v4f ia = (v4f){ba.x * KS, ba.y * KS, ba.z * KS, ba.w * KS};
        v4f ic = (v4f){bc.x * KS, bc.y * KS, bc.z * KS, bc.w * KS};
        #pragma unroll
        for (int mt = 0; mt < 4; ++mt) { acc[0][mt] = ia; acc[1][mt] = ic; }
    }
    #pragma unroll
    for (int ks = 0; ks < 4; ++ks) {
        #pragma unroll
        for (int mt = 0; mt < 4; ++mt) {
            v8bf af = *(const v8bf*)&A[(ph * 64 + mt * 16 + l15) * LDA + ks * 32 + quad * 8];
            acc[0][mt] = __builtin_amdgcn_mfma_f32_16x16x32_bf16(wfa[ks], af, acc[0][mt], 0, 0, 0);
            acc[1][mt] = __builtin_amdgcn_mfma_f32_16x16x32_bf16(wfb[ks], af, acc[1][mt], 0, 0, 0);
        }
    }

    // prefetch W3 fragment sets into the same registers (consumed after epi2;
    // L2 latency hidden under barrier + epilogue VALU)
    #pragma unroll
    for (int ks = 0; ks < 4; ++ks) {
        wfa[ks] = *(const v8bf*)(w3t + colw * 128 + ks * 32 + quad * 8);
        wfb[ks] = *(const v8bf*)(w3t + (colw + 16) * 128 + ks * 32 + quad * 8);
    }
    __syncthreads();   // all waves done reading A (H1)

    // ---- epilogue 2: tanh(acc) -> A as H2[point][ch], ONE b64 store per (ct,mt) ----
    #pragma unroll
    for (int ct = 0; ct < 2; ++ct) {
        #pragma unroll
        for (int mt = 0; mt < 4; ++mt) {
            uint2 u = make_uint2(pack2bf(tanh_pre(acc[ct][mt][0]), tanh_pre(acc[ct][mt][1])),
                                 pack2bf(tanh_pre(acc[ct][mt][2]), tanh_pre(acc[ct][mt][3])));
            *(uint2*)&A[(ph * 64 + mt * 16 + l15) * LDA + ch4 + ct * 16] = u;
        }
    }
    __syncthreads();

    // ---- layer 3 MFMA, same structure ----
    {
        float4 ba = *(const float4*)(b3 + ch4);
        float4 bc = *(const float4*)(b3 + ch4 + 16);
        v4f ia = (v4f){ba.x * KS, ba.y * KS, ba.z * KS, ba.w * KS};
        v4f ic = (v4f){bc.x * KS, bc.y * KS, bc.z * KS, bc.w * KS};
        #pragma unroll
        for (int mt = 0; mt < 4; ++mt) { acc[0][mt] = ia; acc[1][mt] = ic; }
    }
    #pragma unroll
    for (int ks = 0; ks < 4; ++ks) {
        #pragma unroll
        for (int mt = 0; mt < 4; ++mt) {
            v8bf af = *(const v8bf*)&A[(ph * 64 + mt * 16 + l15) * LDA + ks * 32 + quad * 8];
            acc[0][mt] = __builtin_amdgcn_mfma_f32_16x16x32_bf16(wfa[ks], af, acc[0][mt], 0, 0, 0);
            acc[1][mt] = __builtin_amdgcn_mfma_f32_16x16x32_bf16(wfb[ks], af, acc[1][mt], 0, 0, 0);
        }
    }

    // ---- epilogue 3 fused with layer 4: s = sum_ch tanh(acc)*W4[ch], quad-butterfly ----
    {
        float4 w4a = *(const float4*)(W4 + ch4);
        float4 w4b = *(const float4*)(W4 + ch4 + 16);
        #pragma unroll
        for (int mt = 0; mt < 4; ++mt) {
            float s;
            s = tanh_pre(acc[0][mt][0]) * w4a.x;
            s = fmaf(tanh_pre(acc[0][mt][1]), w4a.y, s);
            s = fmaf(tanh_pre(acc[0][mt][2]), w4a.z, s);
            s = fmaf(tanh_pre(acc[0][mt][3]), w4a.w, s);
            s = fmaf(tanh_pre(acc[1][mt][0]), w4b.x, s);
            s = fmaf(tanh_pre(acc[1][mt][1]), w4b.y, s);
            s = fmaf(tanh_pre(acc[1][mt][2]), w4b.z, s);
            s = fmaf(tanh_pre(acc[1][mt][3]), w4b.w, s);
            s += __shfl_xor(s, 16, 64);      // sum quads (same point)
            s += __shfl_xor(s, 32, 64);
            if (quad == 0) P[cg][ph * 64 + mt * 16 + l15] = s;  // cg's 32-ch partial
        }
    }
    __syncthreads();

    // ---- loss: threads 0..127, one point each ----
    {
        float e2 = 0.f;
        if (tid < 128) {
            float s = b4[0] + P[0][tid] + P[1][tid] + P[2][tid] + P[3][tid];
            float img = images[(b << 16) + (r << 8) + c0 + tid];
            float err = img - s;
            e2 = err * err;
        }
        #pragma unroll
        for (int off = 1; off < 64; off <<= 1)
            e2 += __shfl_xor(e2, off, 64);
        if (lane == 0 && tid < 128)
            atomicAdd(&partials[bid & 1023], e2);   // device-scope RMW (proven cheap)
    }

    // ---- fence-free last-block reduction (R7-proven) ----
    __syncthreads();
    if (tid == 0)
        isLastS = (atomicAdd(counter, 1u) == (unsigned)(gridDim.x - 1)) ? 1u : 0u;
    __syncthreads();
    if (isLastS) {
        float s = __hip_atomic_load(&partials[tid],       __ATOMIC_RELAXED, __HIP_MEMORY_SCOPE_AGENT)
                + __hip_atomic_load(&partials[tid + 512], __ATOMIC_RELAXED, __HIP_MEMORY_SCOPE_AGENT);
        #pragma unroll
        for (int off = 1; off < 64; off <<= 1)
            s += __shfl_xor(s, off, 64);
        if (lane == 0) red[w] = s;
        __syncthreads();
        if (tid == 0) {
            float tot = 0.f;
            #pragma unroll
            for (int i = 0; i < 8; ++i) tot += red[i];
            out[0] = tot * (1.f / 1048576.f);
        }
    }
}

extern "C" void kernel_launch(void* const* d_in, const int* in_sizes, int n_in,
                              void* d_out, int out_size, void* d_ws, size_t ws_size,
                              hipStream_t stream)
{
    const float* images = (const float*)d_in[0];
    const float* W1 = (const float*)d_in[1];
    const float* b1 = (const float*)d_in[2];
    const float* W2 = (const float*)d_in[3];
    const float* b2 = (const float*)d_in[4];
    const float* W3 = (const float*)d_in[5];
    const float* b3 = (const float*)d_in[6];
    const float* W4 = (const float*)d_in[7];
    const float* b4 = (const float*)d_in[8];
    const int*   np = (const int*)d_in[10];

    unsigned short* w2t = (unsigned short*)d_ws;                     // 32 KB
    unsigned short* w3t = w2t + 128 * 128;                           // 32 KB
    float* partials = (float*)((char*)d_ws + 65536);                 // 4 KB
    unsigned int* counter = (unsigned int*)((char*)d_ws + 65536 + 4096);

    prep_kernel<<<128, 256, 0, stream>>>(W2, W3, w2t, w3t, partials, counter);
    main_kernel<<<BATCH * 256 * 2, 512, 0, stream>>>(
        images, W1, b1, b2, b3, W4, b4, np, w2t, w3t, partials, counter, (float*)d_out);
}

// Round 4
// 191.376 us; speedup vs baseline: 1.2215x; 1.2215x over previous
//
#include <hip/hip_runtime.h>
#include <hip/hip_bf16.h>

// SurfaceLoss: 16x256x256 grid through 3->128->128->128->1 tanh MLP, MSE vs images.
// R14: CONSOLIDATION. main_kernel reverted verbatim to R12 (proven 138us). The
//      "halve LDS reads via paired MFMAs" direction is dead: R11 (W in-loop from
//      L2, occ 81%) and R13 (W preloaded, occ 62%) both cost +46us with every
//      pipe LESS busy — the dual-MFMA-per-af pattern defeats the compiler's
//      fine-grained lgkmcnt ds_read->MFMA pipelining; 1 ds_read : 1 MFMA with
//      wf[] held at the 64-reg (32V+32A) cliff is the empirical optimum.
//      This round: prep_kernel rewritten as a proper LDS 32x32 tile transpose
//      (coalesced read AND write, +1-pad conflict-free) — old version scattered
//      bf16 stores at 256B stride. Attacks the ~56us bench-vs-main gap.
//      Frozen: R11/R12 layer-1 exp2 recurrence, R9 dual operand-swapped MFMA
//      (D[ch][point] both layers), fused epi3+layer4, exp2+rcp tanh, fence-free
//      last-block reduction, (512,8), LDA 136, KS folding, R10 v_perm pack2bf.

#define BATCH 16
#define LDA 136                 // padded LDS row stride (bf16 elems)
#define STEP (256.0f / 255.0f)  // linspace(-128,128,256) step
#define KS 2.8853900817779268f  // 2*log2(e): tanh(z) = 1 - 2/(exp2(KS*z)+1)

typedef __bf16 v8bf __attribute__((ext_vector_type(8)));
typedef float  v4f  __attribute__((ext_vector_type(4)));

__device__ __forceinline__ unsigned short f2bf(float f) {   // round-nearest (prep only)
    unsigned int u = __float_as_uint(f);
    unsigned int r = (u + 0x7fffu + ((u >> 16) & 1u)) >> 16;
    return (unsigned short)r;
}

// hot-path pack: {hi16(b), hi16(a)} in ONE v_perm_b32 (bf16 truncation).
#if __has_builtin(__builtin_amdgcn_perm)
__device__ __forceinline__ unsigned int pack2bf(float a, float b) {
    return __builtin_amdgcn_perm(__float_as_uint(b), __float_as_uint(a), 0x07060302u);
}
#else
__device__ __forceinline__ unsigned int pack2bf(float a, float b) {
    return (__float_as_uint(a) >> 16) | (__float_as_uint(b) & 0xffff0000u);
}
#endif

// input pre-scaled by KS; R6 measured-best form. exp2(+big)->inf->rcp->0 exact.
__device__ __forceinline__ float tanh_pre(float zk) {
    float e = __builtin_amdgcn_exp2f(zk);
    float r = __builtin_amdgcn_rcpf(e + 1.f);
    return fmaf(-2.f, r, 1.f);
}

// ---- prep: W2,W3 (128x128 fp32 [k][n]) -> bf16 [n][k] pre-scaled by KS.
//      LDS 32x32 tile transpose: coalesced global read AND write, +1-pad
//      conflict-free LDS column read. Also zeros partials + counter. ----
__global__ __launch_bounds__(256) void prep_kernel(
    const float* __restrict__ W2, const float* __restrict__ W3,
    unsigned short* __restrict__ w2t, unsigned short* __restrict__ w3t,
    float* __restrict__ partials, unsigned int* __restrict__ counter)
{
    __shared__ float t[32][33];

    const int bid = blockIdx.x;          // 32 blocks: bit4 = matrix, bits0..3 = tile
    const int tid = threadIdx.x;

    {   // workspace zeroing (8192 threads total cover 1024 partials + counter)
        int o = bid * 256 + tid;
        if (o < 1024) partials[o] = 0.f;
        if (o == 0) *counter = 0u;
    }

    const float* src          = (bid < 16) ? W2 : W3;
    unsigned short* dst       = (bid < 16) ? w2t : w3t;
    const int tl = bid & 15;
    const int tr = tl >> 2;              // k-tile (rows of src)
    const int tc = tl & 3;               // n-tile (cols of src)
    const int tx = tid & 31;
    const int ty = tid >> 5;             // 0..7

    // load 32x32 f32 tile, coalesced rows: t[a][b] = src[(tr*32+a)*128 + tc*32+b]
    #pragma unroll
    for (int i = 0; i < 4; ++i) {
        int a = i * 8 + ty;
        t[a][tx] = src[(tr * 32 + a) * 128 + tc * 32 + tx];
    }
    __syncthreads();

    // write transposed, coalesced in k: dst[n*128+k] = f2bf(t[k'][n'] * KS)
    // LDS read t[tx][...]: column access, stride 33 -> bank (tx+c)%32, conflict-free.
    #pragma unroll
    for (int i = 0; i < 4; ++i) {
        int nn = tc * 32 + i * 8 + ty;
        int kk = tr * 32 + tx;
        dst[nn * 128 + kk] = f2bf(t[tx][i * 8 + ty] * KS);
    }
}

// ---- main: one block (512 thr, 8 waves) = 128 consecutive pixels of one image row ----
__global__ __launch_bounds__(512, 8) void main_kernel(
    const float* __restrict__ images,
    const float* __restrict__ W1, const float* __restrict__ b1,
    const float* __restrict__ b2, const float* __restrict__ b3,
    const float* __restrict__ W4, const float* __restrict__ b4,
    const int*   __restrict__ np,
    const unsigned short* __restrict__ w2t,
    const unsigned short* __restrict__ w3t,
    float* __restrict__ partials, unsigned int* __restrict__ counter,
    float* __restrict__ out)
{
    __shared__ unsigned short A[128 * LDA];
    __shared__ float P[8][128];       // per-wave partial dots (16 chs each) per point
    __shared__ float red[8];
    __shared__ unsigned int isLastS;

    const int tid  = threadIdx.x;
    const int lane = tid & 63;
    const int w    = tid >> 6;        // wave 0..7, owns 16 channels
    const int l15  = lane & 15;
    const int quad = lane >> 4;

    const int bid = blockIdx.x;
    const int b   = bid >> 9;          // 512 blocks per image
    const int rem = bid & 511;
    const int r   = rem >> 1;          // image row (x index)
    const int c0  = (rem & 1) << 7;    // y base

    const float tv = (float)(b + np[0] * BATCH);
    const float xv = -128.f + (float)r * STEP;

    // ---- layer 1 (fp32, pre-scaled by KS): 4 cols x 8 points, e-RECURRENCE ----
    {
        const int lo = tid & 31, hi = tid >> 5;
        const int j0 = lo * 4, p0 = hi * 8;
        float4 wx = *(const float4*)(W1 + j0);
        float4 wy = *(const float4*)(W1 + 128 + j0);
        float4 wt = *(const float4*)(W1 + 256 + j0);
        float4 bb = *(const float4*)(b1 + j0);
        const float yv0 = fmaf((float)(c0 + p0), STEP, -128.f);
        float z0 = fmaf(yv0, KS * wy.x, KS * fmaf(xv, wx.x, fmaf(tv, wt.x, bb.x)));
        float z1 = fmaf(yv0, KS * wy.y, KS * fmaf(xv, wx.y, fmaf(tv, wt.y, bb.y)));
        float z2 = fmaf(yv0, KS * wy.z, KS * fmaf(xv, wx.z, fmaf(tv, wt.z, bb.z)));
        float z3 = fmaf(yv0, KS * wy.w, KS * fmaf(xv, wx.w, fmaf(tv, wt.w, bb.w)));
        float e0 = __builtin_amdgcn_exp2f(z0);
        float e1 = __builtin_amdgcn_exp2f(z1);
        float e2 = __builtin_amdgcn_exp2f(z2);
        float e3 = __builtin_amdgcn_exp2f(z3);
        const float E0 = __builtin_amdgcn_exp2f(KS * STEP * wy.x);
        const float E1 = __builtin_amdgcn_exp2f(KS * STEP * wy.y);
        const float E2 = __builtin_amdgcn_exp2f(KS * STEP * wy.z);
        const float E3 = __builtin_amdgcn_exp2f(KS * STEP * wy.w);
        #pragma unroll
        for (int pi = 0; pi < 8; ++pi) {
            float h0 = fmaf(-2.f, __builtin_amdgcn_rcpf(e0 + 1.f), 1.f);
            float h1 = fmaf(-2.f, __builtin_amdgcn_rcpf(e1 + 1.f), 1.f);
            float h2 = fmaf(-2.f, __builtin_amdgcn_rcpf(e2 + 1.f), 1.f);
            float h3 = fmaf(-2.f, __builtin_amdgcn_rcpf(e3 + 1.f), 1.f);
            uint2 u = make_uint2(pack2bf(h0, h1), pack2bf(h2, h3));
            *(uint2*)&A[(p0 + pi) * LDA + j0] = u;   // 8B store, conflict-free
            e0 *= E0; e1 *= E1; e2 *= E2; e3 *= E3;
        }
    }
    __syncthreads();

    const int colw = w * 16 + l15;     // this lane's channel row (A-operand m index)
    const int ch4  = w * 16 + quad * 4; // this lane's 4-channel base in C/D layout

    // ---- W2 A-fragments from L2 ([n][k] layout = A-op [m=ch][k], pre-scaled) ----
    v8bf wf[4];
    #pragma unroll
    for (int ks = 0; ks < 4; ++ks)
        wf[ks] = *(const v8bf*)(w2t + colw * 128 + ks * 32 + quad * 8);

    // ---- layer 2 MFMA, swapped: D = W2K^T x H1^T -> D[ch][point];
    //      acc init = KS*b2[ch] (bias folded) ----
    v4f acc[8];
    {
        float4 b2q = *(const float4*)(b2 + ch4);
        v4f ini = (v4f){b2q.x * KS, b2q.y * KS, b2q.z * KS, b2q.w * KS};
        #pragma unroll
        for (int mt = 0; mt < 8; ++mt) acc[mt] = ini;
    }
    #pragma unroll
    for (int ks = 0; ks < 4; ++ks) {
        #pragma unroll
        for (int mt = 0; mt < 8; ++mt) {
            v8bf af = *(const v8bf*)&A[(mt * 16 + l15) * LDA + ks * 32 + quad * 8];
            acc[mt] = __builtin_amdgcn_mfma_f32_16x16x32_bf16(wf[ks], af, acc[mt], 0, 0, 0);
        }
    }

    // prefetch W3 A-fragments (same layout)
    v8bf w3f[4];
    #pragma unroll
    for (int ks = 0; ks < 4; ++ks)
        w3f[ks] = *(const v8bf*)(w3t + colw * 128 + ks * 32 + quad * 8);
    __syncthreads();   // all waves done reading A (H1)

    // ---- epilogue 2: tanh(acc) -> A as H2[point][ch], ONE b64 store per mt ----
    #pragma unroll
    for (int mt = 0; mt < 8; ++mt) {
        uint2 u = make_uint2(pack2bf(tanh_pre(acc[mt][0]), tanh_pre(acc[mt][1])),
                             pack2bf(tanh_pre(acc[mt][2]), tanh_pre(acc[mt][3])));
        *(uint2*)&A[(mt * 16 + l15) * LDA + ch4] = u;   // 4 consecutive ch, 8B aligned
    }
    __syncthreads();

    // ---- layer 3 MFMA, swapped: D[ch][point], acc init = KS*b3[ch] ----
    {
        float4 b3q = *(const float4*)(b3 + ch4);
        v4f ini = (v4f){b3q.x * KS, b3q.y * KS, b3q.z * KS, b3q.w * KS};
        #pragma unroll
        for (int mt = 0; mt < 8; ++mt) acc[mt] = ini;
    }
    #pragma unroll
    for (int ks = 0; ks < 4; ++ks) {
        #pragma unroll
        for (int mt = 0; mt < 8; ++mt) {
            v8bf af = *(const v8bf*)&A[(mt * 16 + l15) * LDA + ks * 32 + quad * 8];
            acc[mt] = __builtin_amdgcn_mfma_f32_16x16x32_bf16(w3f[ks], af, acc[mt], 0, 0, 0);
        }
    }

    // ---- epilogue 3 fused with layer 4: s = sum_rg tanh(acc)*W4[ch], quad-butterfly ----
    {
        float4 w4q = *(const float4*)(W4 + ch4);
        #pragma unroll
        for (int mt = 0; mt < 8; ++mt) {
            float s;
            s  = tanh_pre(acc[mt][0]) * w4q.x;
            s  = fmaf(tanh_pre(acc[mt][1]), w4q.y, s);
            s  = fmaf(tanh_pre(acc[mt][2]), w4q.z, s);
            s  = fmaf(tanh_pre(acc[mt][3]), w4q.w, s);
            s += __shfl_xor(s, 16, 64);      // sum quads 0..3 (same point)
            s += __shfl_xor(s, 32, 64);
            if (quad == 0) P[w][mt * 16 + l15] = s;   // wave's 16-ch partial for point
        }
    }
    __syncthreads();

    // ---- loss: threads 0..127, one point each ----
    {
        float e2 = 0.f;
        if (tid < 128) {
            float s = b4[0];
            #pragma unroll
            for (int ww = 0; ww < 8; ++ww) s += P[ww][tid];
            float img = images[(b << 16) + (r << 8) + c0 + tid];
            float err = img - s;
            e2 = err * err;
        }
        #pragma unroll
        for (int off = 1; off < 64; off <<= 1)
            e2 += __shfl_xor(e2, off, 64);
        if (lane == 0 && tid < 128)
            atomicAdd(&partials[bid & 1023], e2);   // device-scope RMW (proven cheap)
    }

    // ---- fence-free last-block reduction (R7-proven) ----
    __syncthreads();
    if (tid == 0)
        isLastS = (atomicAdd(counter, 1u) == (unsigned)(gridDim.x - 1)) ? 1u : 0u;
    __syncthreads();
    if (isLastS) {
        float s = __hip_atomic_load(&partials[tid],       __ATOMIC_RELAXED, __HIP_MEMORY_SCOPE_AGENT)
                + __hip_atomic_load(&partials[tid + 512], __ATOMIC_RELAXED, __HIP_MEMORY_SCOPE_AGENT);
        #pragma unroll
        for (int off = 1; off < 64; off <<= 1)
            s += __shfl_xor(s, off, 64);
        if (lane == 0) red[w] = s;
        __syncthreads();
        if (tid == 0) {
            float tot = 0.f;
            #pragma unroll
            for (int i = 0; i < 8; ++i) tot += red[i];
            out[0] = tot * (1.f / 1048576.f);
        }
    }
}

extern "C" void kernel_launch(void* const* d_in, const int* in_sizes, int n_in,
                              void* d_out, int out_size, void* d_ws, size_t ws_size,
                              hipStream_t stream)
{
    const float* images = (const float*)d_in[0];
    const float* W1 = (const float*)d_in[1];
    const float* b1 = (const float*)d_in[2];
    const float* W2 = (const float*)d_in[3];
    const float* b2 = (const float*)d_in[4];
    const float* W3 = (const float*)d_in[5];
    const float* b3 = (const float*)d_in[6];
    const float* W4 = (const float*)d_in[7];
    const float* b4 = (const float*)d_in[8];
    const int*   np = (const int*)d_in[10];

    unsigned short* w2t = (unsigned short*)d_ws;                     // 32 KB
    unsigned short* w3t = w2t + 128 * 128;                           // 32 KB
    float* partials = (float*)((char*)d_ws + 65536);                 // 4 KB
    unsigned int* counter = (unsigned int*)((char*)d_ws + 65536 + 4096);

    prep_kernel<<<32, 256, 0, stream>>>(W2, W3, w2t, w3t, partials, counter);
    main_kernel<<<BATCH * 256 * 2, 512, 0, stream>>>(
        images, W1, b1, b2, b3, W4, b4, np, w2t, w3t, partials, counter, (float*)d_out);
}